// Round 20
// baseline (217.776 us; speedup 1.0000x reference)
//
#include <hip/hip_runtime.h>
#include <stdint.h>

#define DEVI __device__ __forceinline__

typedef __attribute__((ext_vector_type(8))) __bf16 bf16x8;
typedef __attribute__((ext_vector_type(4))) __bf16 bf16x4;
typedef __attribute__((ext_vector_type(4))) float f32x4;
typedef __attribute__((ext_vector_type(4))) unsigned short u16x4;
typedef __attribute__((ext_vector_type(4))) unsigned int u32x4;
typedef unsigned short u16;

constexpr int Bn = 4, Sn = 2048, Dn = 1024, Hn = 16;
constexpr int Mn = Bn * Sn;                               // 8192
constexpr float QSCALE = 1.4426950408889634f / 32.0f;     // log2(e)/sqrt(D): folds softmax scale + exp2 base
// Fixed softmax shift, folded into the FIRST QK^T MFMA's C operand:
// energies are ~N(0,1) so sc <= ~8 << 16; P = exp2(sc-16) <= 2^-8,
// l ~ 0.04 in f32. Softmax is shift-invariant.
constexpr float SSHIFT = -16.0f;

// ---------- helpers ----------
DEVI u16 f2bf(float f) {                                  // RNE f32 -> bf16 bits
  uint32_t u = __builtin_bit_cast(uint32_t, f);
  u += 0x7fffu + ((u >> 16) & 1u);
  return (u16)(u >> 16);
}

typedef __attribute__((address_space(1))) void gvoid;
typedef __attribute__((address_space(3))) void lvoid;
DEVI void gload_lds16(const void* g, void* l) {
  // LDS dest is wave-uniform base + lane*16 (pass base only)
  __builtin_amdgcn_global_load_lds((gvoid*)(uintptr_t)g,
                                   (lvoid*)(uint32_t)(uintptr_t)l, 16, 0, 0);
}

DEVI f32x4 mfma16(bf16x8 a, bf16x8 b, f32x4 c) {
  return __builtin_amdgcn_mfma_f32_16x16x32_bf16(a, b, c, 0, 0, 0);
}

// ---------- cast fp32 -> bf16 (WEIGHTS ONLY; activations read fp32 by qkv) ----------
struct CastArgs {
  const float* src[4];
  u16* dst[4];
  int n[4];
};

__global__ __launch_bounds__(256) void cast_kernel(CastArgs a) {
  const int seg = blockIdx.y;
  const float* __restrict__ src = a.src[seg];
  u16* __restrict__ dst = a.dst[seg];
  const int n = a.n[seg];
  const int stride = gridDim.x * 256 * 4;
  for (int i = (blockIdx.x * 256 + threadIdx.x) * 4; i < n; i += stride) {
    const float4 v = *reinterpret_cast<const float4*>(src + i);
    u16x4 p;
    p[0] = f2bf(v.x); p[1] = f2bf(v.y); p[2] = f2bf(v.z); p[3] = f2bf(v.w);
    *reinterpret_cast<u16x4*>(dst + i) = p;
  }
}

// ================== QKV GEMM: BM=128, BN=256, fp32-A, latency-matched depths ==================
// 512 thr, 8 waves (2 M x 4 N), acc[4][4]/wave, 16 MFMA/tile/wave.
// R19 failed because A (COLD HBM, ~900cyc) had only 1-tile prefetch depth.
// Fix: A fp32 3-deep (2-tile depth), B bf16 2-deep (1-tile depth -- B is the
// L2-resident 2MB weight matrix, ~200cyc). LDS 3x16 + 2x16 = 80 KB -> 2 blk/CU.
// Per tile t: wait vmcnt(2) [queue is A(t)^2,B(t)^2,A(t+1)^2 in issue order;
// drains A(t)+B(t), leaves A(t+1) in flight] -> barrier -> stage B(t+1) THEN
// A(t+2) (order keeps the drain pattern uniform) -> compute.
// A->bf16 conversion on the LDS read (8 ds_read_b128 + 16 cvt_pk /tile/lane).
// Layouts (R19-verified): A fp32 [128 rows=m][8 slots], slot=(k>>2)^(row&7);
// B bf16 [2 halves x 64 rows][8 slots], n=half*64+row+128*(us>>2), k=(us&3)*8.
struct QKVArgs {
  const float *Aq, *Ak, *Av;
  const u16 *Wq, *Wk, *Wv;
  const float *bq, *bk, *bv;
  u16 *Qh, *Kh, *Vt;
};

__global__ __launch_bounds__(512, 4)
void qkv_gemm(QKVArgs a) {
  __shared__ __align__(16) float Asf[3][128 * 32];   // 48 KB fp32 A (2-tile depth)
  __shared__ __align__(16) u16 Bs[2][256 * 32];      // 32 KB bf16 B (1-tile depth)

  const int raw = blockIdx.x;
  const int swz = (raw & 7) * 96 + (raw >> 3);       // bijective: 768 = 8*96
  const int which = swz >> 8;                        // block-uniform
  const int bid = swz & 255;
  const float* __restrict__ A = which == 0 ? a.Aq : which == 1 ? a.Ak : a.Av;
  const u16* __restrict__ Bt  = which == 0 ? a.Wq : which == 1 ? a.Wk : a.Wv;
  const float* __restrict__ bias = which == 0 ? a.bq : which == 1 ? a.bk : a.bv;

  const int mt = bid >> 2, nt = bid & 3;
  const int m0 = mt * 128, n0 = nt * 256;

  const int tid = threadIdx.x, lane = tid & 63, w = tid >> 6;
  const int wr = w >> 2, wc = w & 3;                 // 2 M x 4 N
  const int c = lane & 15, g = lane >> 4;

  // staging: chunk tid -> (row = tid>>3, lds slot = tid&7); src slot us = (tid&7)^(row&7)
  const int arow = tid >> 3;
  const int aus = (tid & 7) ^ (arow & 7);
  const float* aSrc = A + (size_t)(m0 + arow) * 1024 + aus * 4;           // 16B fp32
  const u16* bSrc0 = Bt + (size_t)(n0 + arow + 128 * (aus >> 2)) * 1024 + (aus & 3) * 8;
  const u16* bSrc1 = bSrc0 + (size_t)64 * 1024;
  const int ldsOff = w * 1024;                       // bytes; HW adds lane*16

  // read bases (128B rows, 8-slot XOR -> 2 lanes/slot within 16-lane group = free)
  const int aB0 = (wr * 64 + c) * 128 + (((g * 2) ^ (c & 7)) << 4);       // fp32 A
  const int bBr = (wc & 1) * 8192 + c * 128
                  + ((((wc >> 1) * 4 + g) ^ (c & 7)) << 4);               // bf16 B

  f32x4 acc[4][4] = {};

#define QSTAGE_A(BUF, KT_)                                                    \
  {                                                                           \
    gload_lds16(aSrc + (KT_), (char*)Asf[BUF] + ldsOff);                      \
    gload_lds16(aSrc + 65536 + (KT_), (char*)Asf[BUF] + 8192 + ldsOff);       \
  }
#define QSTAGE_B(BUF, KT_)                                                    \
  {                                                                           \
    gload_lds16(bSrc0 + (KT_), (char*)Bs[BUF] + ldsOff);                      \
    gload_lds16(bSrc1 + (KT_), (char*)Bs[BUF] + 8192 + ldsOff);               \
  }

#define QTILE(AR, AW, BR, BW, KT)                                             \
  {                                                                           \
    asm volatile("s_waitcnt vmcnt(2)" ::: "memory");                          \
    __builtin_amdgcn_sched_barrier(0);                                        \
    __builtin_amdgcn_s_barrier();                                             \
    __builtin_amdgcn_sched_barrier(0);                                        \
    QSTAGE_B(BW, ((KT) + 32) & 1023);                                         \
    QSTAGE_A(AW, ((KT) + 64) & 1023);                                         \
    bf16x8 bfq[4];                                                            \
    _Pragma("unroll")                                                         \
    for (int ni = 0; ni < 4; ++ni)                                            \
      bfq[ni] = *(const bf16x8*)((const char*)Bs[BR] + bBr + ni * 2048);      \
    bf16x8 af[4];                                                             \
    _Pragma("unroll")                                                         \
    for (int mi = 0; mi < 4; ++mi) {                                          \
      const f32x4 alo = *(const f32x4*)((const char*)Asf[AR] + (aB0 + mi * 2048));        \
      const f32x4 ahi = *(const f32x4*)((const char*)Asf[AR] + ((aB0 ^ 16) + mi * 2048)); \
      uint32_t w0_, w1_, w2_, w3_;                                            \
      asm("v_cvt_pk_bf16_f32 %0, %1, %2" : "=v"(w0_) : "v"(alo[0]), "v"(alo[1])); \
      asm("v_cvt_pk_bf16_f32 %0, %1, %2" : "=v"(w1_) : "v"(alo[2]), "v"(alo[3])); \
      asm("v_cvt_pk_bf16_f32 %0, %1, %2" : "=v"(w2_) : "v"(ahi[0]), "v"(ahi[1])); \
      asm("v_cvt_pk_bf16_f32 %0, %1, %2" : "=v"(w3_) : "v"(ahi[2]), "v"(ahi[3])); \
      const u32x4 uv_ = {w0_, w1_, w2_, w3_};                                 \
      af[mi] = __builtin_bit_cast(bf16x8, uv_);                               \
    }                                                                         \
    __builtin_amdgcn_s_setprio(1);                                            \
    _Pragma("unroll")                                                         \
    for (int mi = 0; mi < 4; ++mi)                                            \
      _Pragma("unroll")                                                       \
      for (int ni = 0; ni < 4; ++ni)                                          \
        acc[mi][ni] = mfma16(af[mi], bfq[ni], acc[mi][ni]);                   \
    __builtin_amdgcn_s_setprio(0);                                            \
  }

  // prologue (issue order matters): A(0), B(0), A(1) -> queue [A0,B0,A1];
  // tile-0 wait vmcnt(2) drains A0+B0, leaves A1 in flight
  QSTAGE_A(0, 0);
  QSTAGE_B(0, 0);
  QSTAGE_A(1, 32);
  // 32 tiles, period 6: tile t uses AR=t%3, BR=t&1; stages BW=(t+1)&1, AW=(t+2)%3
  for (int kt = 0; kt < 960; kt += 192) {
    QTILE(0, 2, 0, 1, kt);
    QTILE(1, 0, 1, 0, kt + 32);
    QTILE(2, 1, 0, 1, kt + 64);
    QTILE(0, 2, 1, 0, kt + 96);
    QTILE(1, 0, 0, 1, kt + 128);
    QTILE(2, 1, 1, 0, kt + 160);
  }
  QTILE(0, 2, 0, 1, 960);
  QTILE(1, 0, 1, 0, 992);
#undef QTILE
#undef QSTAGE_B
#undef QSTAGE_A

  // epilogue; C/D layout: col = lane&15 (n), row = (lane>>4)*4 + reg (m)
  #pragma unroll
  for (int mi = 0; mi < 4; ++mi) {
    #pragma unroll
    for (int ni = 0; ni < 4; ++ni) {
      const int n = n0 + wc * 64 + ni * 16 + c;
      const float bv = bias[n];
      const int mb = m0 + wr * 64 + mi * 16 + g * 4;
      const f32x4 v = acc[mi][ni];
      const int h = n >> 6, hd = n & 63;
      if (which == 2) {
        const int b = mb >> 11, s = mb & 2047;   // 4 consecutive s, same b
        u16x4 pk;
        #pragma unroll
        for (int j = 0; j < 4; ++j) pk[j] = f2bf(v[j] + bv);
        *(u16x4*)(a.Vt + ((size_t)((b * Hn + h) * 64 + hd)) * Sn + s) = pk;
      } else {
        u16* dst = which == 0 ? a.Qh : a.Kh;
        const float sc = which == 0 ? QSCALE : 1.0f;
        #pragma unroll
        for (int j = 0; j < 4; ++j) {
          const int m = mb + j;
          const int b = m >> 11, s = m & 2047;
          dst[(((size_t)(b * Hn + h) * Sn + s) << 6) + hd] = f2bf((v[j] + bv) * sc);
        }
      }
    }
  }
}

// ---------- output projection GEMM: fp32 out [M][N] (R17, unchanged) ----------
__global__ __launch_bounds__(512, 4)
void gemm_out(const u16* __restrict__ A, const u16* __restrict__ Bt,
              const float* __restrict__ bias, float* __restrict__ out) {
  __shared__ __align__(16) u16 As[3][128 * 32];
  __shared__ __align__(16) u16 Bs[3][256 * 32];

  const int raw = blockIdx.x;
  const int swz = (raw & 7) * 32 + (raw >> 3);    // bijective: 256 = 8*32
  const int mt = swz >> 2, nt = swz & 3;
  const int m0 = mt * 128, n0 = nt * 256;

  const int tid = threadIdx.x, lane = tid & 63, w = tid >> 6;
  const int wr = w >> 2, wc = w & 3;
  const int c = lane & 15, g = lane >> 4;
  const int arow = tid >> 3;
  const int aus = (tid & 7) ^ (arow & 7);
  const u16* aSrc = A + (size_t)(m0 + arow + 64 * (aus >> 2)) * 1024 + (aus & 3) * 8;
  const u16* bSrc0 = Bt + (size_t)(n0 + arow + 128 * (aus >> 2)) * 1024 + (aus & 3) * 8;
  const u16* bSrc1 = bSrc0 + (size_t)64 * 1024;
  const int ldsOff = w * 1024;
  const int aBr = c * 128 + (((wr * 4 + g) ^ (c & 7)) << 4);
  const int bBr = (wc & 1) * 8192 + c * 128
                  + ((((wc >> 1) * 4 + g) ^ (c & 7)) << 4);

  f32x4 acc[4][4] = {};

#define OSTAGE(BUF, KT_)                                                      \
  {                                                                           \
    gload_lds16(aSrc + (KT_), (char*)As[BUF] + ldsOff);                       \
    gload_lds16(bSrc0 + (KT_), (char*)Bs[BUF] + ldsOff);                      \
    gload_lds16(bSrc1 + (KT_), (char*)Bs[BUF] + 8192 + ldsOff);               \
  }

#define OTILE(BUF, SBUF, KT)                                                  \
  {                                                                           \
    asm volatile("s_waitcnt vmcnt(3)" ::: "memory");                          \
    __builtin_amdgcn_sched_barrier(0);                                        \
    __builtin_amdgcn_s_barrier();                                             \
    __builtin_amdgcn_sched_barrier(0);                                        \
    OSTAGE(SBUF, ((KT) + 64) & 1023);                                         \
    bf16x8 af[4], bfq[4];                                                     \
    _Pragma("unroll")                                                         \
    for (int i = 0; i < 4; ++i)                                               \
      af[i] = *(const bf16x8*)((const char*)As[BUF] + aBr + i * 2048);        \
    _Pragma("unroll")                                                         \
    for (int i = 0; i < 4; ++i)                                               \
      bfq[i] = *(const bf16x8*)((const char*)Bs[BUF] + bBr + i * 2048);       \
    __builtin_amdgcn_s_setprio(1);                                            \
    _Pragma("unroll")                                                         \
    for (int mi = 0; mi < 4; ++mi)                                            \
      _Pragma("unroll")                                                       \
      for (int ni = 0; ni < 4; ++ni)                                          \
        acc[mi][ni] = mfma16(af[mi], bfq[ni], acc[mi][ni]);                   \
    __builtin_amdgcn_s_setprio(0);                                            \
  }

  OSTAGE(0, 0);
  OSTAGE(1, 32);
  for (int kt = 0; kt < 960; kt += 96) {
    OTILE(0, 2, kt);
    OTILE(1, 0, kt + 32);
    OTILE(2, 1, kt + 64);
  }
  OTILE(0, 2, 960);
  OTILE(1, 0, 992);
#undef OTILE
#undef OSTAGE

  #pragma unroll
  for (int mi = 0; mi < 4; ++mi) {
    #pragma unroll
    for (int ni = 0; ni < 4; ++ni) {
      const int n = n0 + wc * 64 + ni * 16 + c;
      const float bv = bias[n];
      const int mb = m0 + wr * 64 + mi * 16 + g * 4;
      const f32x4 v = acc[mi][ni];
      #pragma unroll
      for (int j = 0; j < 4; ++j)
        out[(size_t)(mb + j) * Dn + n] = v[j] + bv;
    }
  }
}

// ---------- flash attention (R16/R17, unchanged) ----------
__global__ __launch_bounds__(512, 4)
void flash_attn(const u16* __restrict__ Q, const u16* __restrict__ K,
                const u16* __restrict__ Vt, u16* __restrict__ X) {
  __shared__ __align__(16) u16 Ks[3][4096];      // 24 KB triple-buffered K
  __shared__ __align__(16) u16 Vs[3][4096];      //  + V tiles

  const int tid = threadIdx.x, lane = tid & 63, w = tid >> 6;   // 8 waves
  const int bid = blockIdx.x;
  const int bh = bid & 63, qt = bid >> 6;
  const int b = bh >> 4, h = bh & 15;
  const int q0 = qt * 128 + w * 16;
  const int c = lane & 15, g = lane >> 4;

  const u16* Qb = Q + (size_t)bh * Sn * 64;
  const u16* Kb = K + (size_t)bh * Sn * 64;
  const u16* Vb = Vt + (size_t)bh * 64 * Sn;

  const int srow = tid >> 3;
  const int scol = (((tid & 7) * 16) ^ ((srow & 7) << 4)) >> 1;   // elements
  const int srcK = srow * 64 + scol;      // + kv*64 per tile
  const int srcV = srow * Sn + scol;      // + kv per tile
  const int ldsOff = w * 1024;            // bytes; HW adds lane*16
#define STAGE(BUF, KV_)                                                   \
  {                                                                       \
    gload_lds16(Kb + (size_t)(KV_) * 64 + srcK, (char*)Ks[BUF] + ldsOff); \
    gload_lds16(Vb + (KV_) + srcV, (char*)Vs[BUF] + ldsOff);              \
  }

  const int laneB0 = c * 128 + ((g * 16) ^ ((c & 7) << 4));
  const int laneB1 = c * 128 + ((64 + g * 16) ^ ((c & 7) << 4));

  bf16x8 qf[2];
  #pragma unroll
  for (int ks = 0; ks < 2; ++ks)
    qf[ks] = *(const bf16x8*)(Qb + (size_t)(q0 + c) * 64 + ks * 32 + g * 8);

  bf16x8 ONES;
  #pragma unroll
  for (int e = 0; e < 8; ++e) ONES[e] = (__bf16)1.0f;
  const f32x4 SINITv = {SSHIFT, SSHIFT, SSHIFT, SSHIFT};

  f32x4 o[4] = {};
  f32x4 lacc = {};              // row-sum l in O layout: q = q0 + g*4 + j
  f32x4 scA[4], scB[4];

#define QK_BLOCK(KB, SCT)                                                     \
  {                                                                           \
    bf16x8 kfr[4];                                                            \
    _Pragma("unroll")                                                         \
    for (int kf = 0; kf < 4; ++kf)                                            \
      kfr[kf] = *(const bf16x8*)((const char*)Ks[KB] + laneB0 + kf * 2048);   \
    __builtin_amdgcn_s_setprio(1);                                            \
    _Pragma("unroll")                                                         \
    for (int kf = 0; kf < 4; ++kf)                                            \
      SCT[kf] = mfma16(kfr[kf], qf[0], SINITv);                               \
    __builtin_amdgcn_s_setprio(0);                                            \
    _Pragma("unroll")                                                         \
    for (int kf = 0; kf < 4; ++kf)                                            \
      kfr[kf] = *(const bf16x8*)((const char*)Ks[KB] + laneB1 + kf * 2048);   \
    __builtin_amdgcn_s_setprio(1);                                            \
    _Pragma("unroll")                                                         \
    for (int kf = 0; kf < 4; ++kf)                                            \
      SCT[kf] = mfma16(kfr[kf], qf[1], SCT[kf]);                              \
    __builtin_amdgcn_s_setprio(0);                                            \
  }

#define FIN_BLOCK(VB, SCT)                                                    \
  {                                                                           \
    uint32_t wvv[4][2];                                                       \
    _Pragma("unroll")                                                         \
    for (int kf = 0; kf < 4; ++kf) {                                          \
      const float p0 = __builtin_exp2f(SCT[kf][0]);                           \
      const float p1 = __builtin_exp2f(SCT[kf][1]);                           \
      const float p2 = __builtin_exp2f(SCT[kf][2]);                           \
      const float p3 = __builtin_exp2f(SCT[kf][3]);                           \
      asm("v_cvt_pk_bf16_f32 %0, %1, %2" : "=v"(wvv[kf][0]) : "v"(p0), "v"(p1)); \
      asm("v_cvt_pk_bf16_f32 %0, %1, %2" : "=v"(wvv[kf][1]) : "v"(p2), "v"(p3)); \
    }                                                                         \
    bf16x8 pa[2];                                                             \
    _Pragma("unroll")                                                         \
    for (int ks2 = 0; ks2 < 2; ++ks2) {                                       \
      uint32_t ua = wvv[2 * ks2][0], ub = wvv[2 * ks2][1];                    \
      uint32_t uc = wvv[2 * ks2 + 1][0], ud = wvv[2 * ks2 + 1][1];            \
      asm("v_permlane32_swap_b32 %0, %1" : "+v"(ua), "+v"(uc));               \
      asm("v_permlane32_swap_b32 %0, %1" : "+v"(ub), "+v"(ud));               \
      asm("v_permlane16_swap_b32 %0, %1" : "+v"(ua), "+v"(uc));               \
      asm("v_permlane16_swap_b32 %0, %1" : "+v"(ub), "+v"(ud));               \
      const u32x4 uv = {ua, ub, uc, ud};                                      \
      pa[ks2] = __builtin_bit_cast(bf16x8, uv);                               \
    }                                                                         \
    lacc = mfma16(pa[0], ONES, lacc);                                         \
    lacc = mfma16(pa[1], ONES, lacc);                                         \
    {                                                                         \
      bf16x8 vfr[4];                                                          \
      _Pragma("unroll")                                                       \
      for (int nd = 0; nd < 4; ++nd)                                          \
        vfr[nd] = *(const bf16x8*)((const char*)Vs[VB] + laneB0 + nd * 2048); \
      __builtin_amdgcn_s_setprio(1);                                          \
      _Pragma("unroll")                                                       \
      for (int nd = 0; nd < 4; ++nd)                                          \
        o[nd] = mfma16(pa[0], vfr[nd], o[nd]);                                \
      __builtin_amdgcn_s_setprio(0);                                          \
      _Pragma("unroll")                                                       \
      for (int nd = 0; nd < 4; ++nd)                                          \
        vfr[nd] = *(const bf16x8*)((const char*)Vs[VB] + laneB1 + nd * 2048); \
      __builtin_amdgcn_s_setprio(1);                                          \
      _Pragma("unroll")                                                       \
      for (int nd = 0; nd < 4; ++nd)                                          \
        o[nd] = mfma16(pa[1], vfr[nd], o[nd]);                                \
      __builtin_amdgcn_s_setprio(0);                                          \
    }                                                                         \
  }

#define PIPE(KB, VB, SB, KV, CURT, NXTT)                                      \
  {                                                                           \
    asm volatile("s_waitcnt vmcnt(0)" ::: "memory");                          \
    __builtin_amdgcn_sched_barrier(0);                                        \
    __builtin_amdgcn_s_barrier();                                             \
    __builtin_amdgcn_sched_barrier(0);                                        \
    STAGE(SB, (KV) + 128);                                                    \
    QK_BLOCK(KB, NXTT);                                                       \
    FIN_BLOCK(VB, CURT);                                                      \
  }

  // prologue: stage tiles 0,1; QK(0) -> scA
  STAGE(0, 0);
  STAGE(1, 64);
  asm volatile("s_waitcnt vmcnt(2)" ::: "memory");   // stage(0) landed
  __builtin_amdgcn_sched_barrier(0);
  __builtin_amdgcn_s_barrier();
  __builtin_amdgcn_sched_barrier(0);
  QK_BLOCK(0, scA);

  // t = 0..29 (staged), 5 x 6-period unroll
  for (int kv = 0; kv < 1920; kv += 384) {
    PIPE(1, 0, 2, kv,       scA, scB);
    PIPE(2, 1, 0, kv + 64,  scB, scA);
    PIPE(0, 2, 1, kv + 128, scA, scB);
    PIPE(1, 0, 2, kv + 192, scB, scA);
    PIPE(2, 1, 0, kv + 256, scA, scB);
    PIPE(0, 2, 1, kv + 320, scB, scA);
  }
  // t = 30: no stage (tile 31 already staged to buf 1 at t=29)
  asm volatile("s_waitcnt vmcnt(0)" ::: "memory");
  __builtin_amdgcn_sched_barrier(0);
  __builtin_amdgcn_s_barrier();
  __builtin_amdgcn_sched_barrier(0);
  QK_BLOCK(1, scB);       // tile 31 from Ks[1]
  FIN_BLOCK(0, scA);      // tile 30 from Vs[0]
  // tail t = 31: finish only; tile 31 lives in buffer 31%3 = 1
  FIN_BLOCK(1, scB);
#undef PIPE
#undef FIN_BLOCK
#undef QK_BLOCK
#undef STAGE

  // epilogue: l already in O layout; normalize and store
  #pragma unroll
  for (int j = 0; j < 4; ++j) {
    const float rn = 1.0f / lacc[j];
    const int s = q0 + g * 4 + j;
    u16* dst = X + (size_t)(b * Sn + s) * Dn + h * 64 + c;
    #pragma unroll
    for (int nd = 0; nd < 4; ++nd)
      dst[nd * 16] = f2bf(o[nd][j] * rn);
  }
}

// ---------- launch ----------
extern "C" void kernel_launch(void* const* d_in, const int* in_sizes, int n_in,
                              void* d_out, int out_size, void* d_ws, size_t ws_size,
                              hipStream_t stream) {
  (void)in_sizes; (void)n_in; (void)out_size; (void)ws_size;
  const float* query = (const float*)d_in[0];
  const float* key_  = (const float*)d_in[1];
  const float* value = (const float*)d_in[2];
  const float* Wq = (const float*)d_in[3];
  const float* bq = (const float*)d_in[4];
  const float* Wk = (const float*)d_in[5];
  const float* bk = (const float*)d_in[6];
  const float* Wv = (const float*)d_in[7];
  const float* bv = (const float*)d_in[8];
  const float* Wo = (const float*)d_in[9];
  const float* bo = (const float*)d_in[10];

  char* ws = (char*)d_ws;
  size_t off = 0;
  auto alloc = [&](size_t bytes) {
    void* p = ws + off;
    off += (bytes + 255) & ~(size_t)255;
    return p;
  };
  const size_t actB = (size_t)Mn * Dn * 2;   // 16 MB
  const size_t wB = (size_t)Dn * Dn * 2;     // 2 MB
  u16* wqb = (u16*)alloc(wB);
  u16* wkb = (u16*)alloc(wB);
  u16* wvb = (u16*)alloc(wB);
  u16* wob = (u16*)alloc(wB);
  u16* Qh = (u16*)alloc(actB);
  u16* Kh = (u16*)alloc(actB);
  u16* Vt = (u16*)alloc(actB);
  u16* Xb = (u16*)alloc(actB);

  CastArgs ca;
  ca.src[0] = Wq; ca.src[1] = Wk; ca.src[2] = Wv; ca.src[3] = Wo;
  ca.dst[0] = wqb; ca.dst[1] = wkb; ca.dst[2] = wvb; ca.dst[3] = wob;
  ca.n[0] = ca.n[1] = ca.n[2] = ca.n[3] = Dn * Dn;
  cast_kernel<<<dim3(512, 4), 256, 0, stream>>>(ca);

  QKVArgs qa;
  qa.Aq = query; qa.Ak = key_; qa.Av = value;
  qa.Wq = wqb; qa.Wk = wkb; qa.Wv = wvb;
  qa.bq = bq; qa.bk = bk; qa.bv = bv;
  qa.Qh = Qh; qa.Kh = Kh; qa.Vt = Vt;
  qkv_gemm<<<dim3(768), 512, 0, stream>>>(qa);

  flash_attn<<<dim3(Bn * Hn * (Sn / 128)), 512, 0, stream>>>(Qh, Kh, Vt, Xb);
  gemm_out<<<dim3(256), 512, 0, stream>>>(Xb, wob, bo, (float*)d_out);
}

// Round 21
// 206.055 us; speedup vs baseline: 1.0569x; 1.0569x over previous
//
#include <hip/hip_runtime.h>
#include <stdint.h>

#define DEVI __device__ __forceinline__

typedef __attribute__((ext_vector_type(8))) __bf16 bf16x8;
typedef __attribute__((ext_vector_type(4))) __bf16 bf16x4;
typedef __attribute__((ext_vector_type(4))) float f32x4;
typedef __attribute__((ext_vector_type(4))) unsigned short u16x4;
typedef __attribute__((ext_vector_type(4))) unsigned int u32x4;
typedef unsigned short u16;

constexpr int Bn = 4, Sn = 2048, Dn = 1024, Hn = 16;
constexpr int Mn = Bn * Sn;                               // 8192
constexpr float QSCALE = 1.4426950408889634f / 32.0f;     // log2(e)/sqrt(D): folds softmax scale + exp2 base
// Fixed softmax shift, folded into the FIRST QK^T MFMA's C operand:
// energies are ~N(0,1) so sc <= ~8 << 16; P = exp2(sc-16) <= 2^-8,
// l ~ 0.04 in f32. Softmax is shift-invariant.
constexpr float SSHIFT = -16.0f;

// ---------- helpers ----------
DEVI u16 f2bf(float f) {                                  // RNE f32 -> bf16 bits
  uint32_t u = __builtin_bit_cast(uint32_t, f);
  u += 0x7fffu + ((u >> 16) & 1u);
  return (u16)(u >> 16);
}

typedef __attribute__((address_space(1))) void gvoid;
typedef __attribute__((address_space(3))) void lvoid;
DEVI void gload_lds16(const void* g, void* l) {
  // LDS dest is wave-uniform base + lane*16 (pass base only)
  __builtin_amdgcn_global_load_lds((gvoid*)(uintptr_t)g,
                                   (lvoid*)(uint32_t)(uintptr_t)l, 16, 0, 0);
}

DEVI f32x4 mfma16(bf16x8 a, bf16x8 b, f32x4 c) {
  return __builtin_amdgcn_mfma_f32_16x16x32_bf16(a, b, c, 0, 0, 0);
}

// ---------- cast fp32 -> bf16 (WEIGHTS ONLY; activations read fp32 by qkv) ----------
struct CastArgs {
  const float* src[4];
  u16* dst[4];
  int n[4];
};

__global__ __launch_bounds__(256) void cast_kernel(CastArgs a) {
  const int seg = blockIdx.y;
  const float* __restrict__ src = a.src[seg];
  u16* __restrict__ dst = a.dst[seg];
  const int n = a.n[seg];
  const int stride = gridDim.x * 256 * 4;
  for (int i = (blockIdx.x * 256 + threadIdx.x) * 4; i < n; i += stride) {
    const float4 v = *reinterpret_cast<const float4*>(src + i);
    u16x4 p;
    p[0] = f2bf(v.x); p[1] = f2bf(v.y); p[2] = f2bf(v.z); p[3] = f2bf(v.w);
    *reinterpret_cast<u16x4*>(dst + i) = p;
  }
}

// ================== QKV GEMM: fp32-A staged via global_load_lds (R18) ==================
// BM=128, BN=128, BK=32, 512 thr, 8 waves (4 M x 2 N), acc[2][4]/wave.
// A staged RAW fp32 into LDS via global_load_lds (register-staged conversion
// serializes -- R14); conversion to bf16 on the LDS->reg read (8 cvt_pk/tile,
// the flash P-path primitive). 3 loads/thread/tile -> vmcnt(3) counted
// protocol. LDS: A fp32 3x16KB + B bf16 3x8KB = 72KB -> 2 blocks/CU.
// This deletes the 144MB activation-cast round-trip (fp32 read + bf16 write
// + bf16 re-read) from the dependency chain.
struct QKVArgs {
  const float *Aq, *Ak, *Av;
  const u16 *Wq, *Wk, *Wv;
  const float *bq, *bk, *bv;
  u16 *Qh, *Kh, *Vt;
};

__global__ __launch_bounds__(512, 4)
void qkv_gemm(QKVArgs a) {
  __shared__ __align__(16) float Asf[3][128 * 32];   // 48 KB fp32 A
  __shared__ __align__(16) u16 Bs[3][128 * 32];      // 24 KB bf16 B

  const int raw = blockIdx.x;
  const int swz = (raw & 7) * 192 + (raw >> 3);      // bijective: 1536 = 8*192
  const int which = swz >> 9;                        // block-uniform
  const int bid = swz & 511;
  const float* __restrict__ A = which == 0 ? a.Aq : which == 1 ? a.Ak : a.Av;
  const u16* __restrict__ Bt  = which == 0 ? a.Wq : which == 1 ? a.Wk : a.Wv;
  const float* __restrict__ bias = which == 0 ? a.bq : which == 1 ? a.bk : a.bv;

  const int mt = bid >> 3, nt = bid & 7;
  const int m0 = mt * 128, n0 = nt * 128;

  const int tid = threadIdx.x, lane = tid & 63, w = tid >> 6;
  const int wr = w >> 1, wc = w & 1;                 // 4 M x 2 N
  const int c = lane & 15, g = lane >> 4;

  // staging: chunk tid -> (row = tid>>3, slot = tid&7); logical us = slot^(row&7)
  const int arow = tid >> 3;
  const int aus = (tid & 7) ^ (arow & 7);
  const float* aSrc = A + (size_t)(m0 + arow) * 1024 + aus * 4;          // 16B fp32
  const u16* bSrc = Bt + (size_t)(n0 + arow + 64 * (aus >> 2)) * 1024 + (aus & 3) * 8;
  const int ldsOff = w * 1024;                       // bytes; HW adds lane*16

  // read bases: A frag (mi, half): row = wr*32+mi*16+c, slot = (g*2+half)^(c&7)
  const int aB0 = (wr * 32 + c) * 128 + (((g * 2) ^ (c & 7)) << 4);
  // B frag (ni): row = ni*16+c, slot = (wc*4+g)^(c&7)
  const int bB0 = c * 128 + (((wc * 4 + g) ^ (c & 7)) << 4);

  f32x4 acc[2][4] = {};

#define QSTAGE(BUF, KT_)                                                      \
  {                                                                           \
    gload_lds16(aSrc + (KT_), (char*)Asf[BUF] + ldsOff);                      \
    gload_lds16(aSrc + 65536 + (KT_), (char*)Asf[BUF] + 8192 + ldsOff);       \
    gload_lds16(bSrc + (KT_), (char*)Bs[BUF] + ldsOff);                      \
  }

#define QTILE(BUF, SBUF, KT)                                                  \
  {                                                                           \
    asm volatile("s_waitcnt vmcnt(3)" ::: "memory");                          \
    __builtin_amdgcn_sched_barrier(0);                                        \
    __builtin_amdgcn_s_barrier();                                             \
    __builtin_amdgcn_sched_barrier(0);                                        \
    QSTAGE(SBUF, ((KT) + 64) & 1023);                                         \
    bf16x8 bfq[4];                                                            \
    _Pragma("unroll")                                                         \
    for (int ni = 0; ni < 4; ++ni)                                            \
      bfq[ni] = *(const bf16x8*)((const char*)Bs[BUF] + bB0 + ni * 2048);     \
    bf16x8 af[2];                                                             \
    _Pragma("unroll")                                                         \
    for (int mi = 0; mi < 2; ++mi) {                                          \
      const f32x4 alo = *(const f32x4*)((const char*)Asf[BUF] + (aB0 + mi * 2048));        \
      const f32x4 ahi = *(const f32x4*)((const char*)Asf[BUF] + ((aB0 ^ 16) + mi * 2048)); \
      uint32_t w0_, w1_, w2_, w3_;                                            \
      asm("v_cvt_pk_bf16_f32 %0, %1, %2" : "=v"(w0_) : "v"(alo[0]), "v"(alo[1])); \
      asm("v_cvt_pk_bf16_f32 %0, %1, %2" : "=v"(w1_) : "v"(alo[2]), "v"(alo[3])); \
      asm("v_cvt_pk_bf16_f32 %0, %1, %2" : "=v"(w2_) : "v"(ahi[0]), "v"(ahi[1])); \
      asm("v_cvt_pk_bf16_f32 %0, %1, %2" : "=v"(w3_) : "v"(ahi[2]), "v"(ahi[3])); \
      const u32x4 uv_ = {w0_, w1_, w2_, w3_};                                 \
      af[mi] = __builtin_bit_cast(bf16x8, uv_);                               \
    }                                                                         \
    __builtin_amdgcn_s_setprio(1);                                            \
    _Pragma("unroll")                                                         \
    for (int mi = 0; mi < 2; ++mi)                                            \
      _Pragma("unroll")                                                       \
      for (int ni = 0; ni < 4; ++ni)                                          \
        acc[mi][ni] = mfma16(af[mi], bfq[ni], acc[mi][ni]);                   \
    __builtin_amdgcn_s_setprio(0);                                            \
  }

  QSTAGE(0, 0);
  QSTAGE(1, 32);
  for (int kt = 0; kt < 960; kt += 96) {
    QTILE(0, 2, kt);
    QTILE(1, 0, kt + 32);
    QTILE(2, 1, kt + 64);
  }
  QTILE(0, 2, 960);
  QTILE(1, 0, 992);
#undef QTILE
#undef QSTAGE

  // epilogue; C/D layout: col = lane&15 (n), row = (lane>>4)*4 + reg (m)
  #pragma unroll
  for (int mi = 0; mi < 2; ++mi) {
    #pragma unroll
    for (int ni = 0; ni < 4; ++ni) {
      const int n = n0 + wc * 64 + ni * 16 + c;
      const float bv = bias[n];
      const int mb = m0 + wr * 32 + mi * 16 + g * 4;
      const f32x4 v = acc[mi][ni];
      const int h = n >> 6, hd = n & 63;
      if (which == 2) {
        const int b = mb >> 11, s = mb & 2047;   // 4 consecutive s, same b
        u16x4 pk;
        #pragma unroll
        for (int j = 0; j < 4; ++j) pk[j] = f2bf(v[j] + bv);
        *(u16x4*)(a.Vt + ((size_t)((b * Hn + h) * 64 + hd)) * Sn + s) = pk;
      } else {
        u16* dst = which == 0 ? a.Qh : a.Kh;
        const float sc = which == 0 ? QSCALE : 1.0f;
        #pragma unroll
        for (int j = 0; j < 4; ++j) {
          const int m = mb + j;
          const int b = m >> 11, s = m & 2047;
          dst[(((size_t)(b * Hn + h) * Sn + s) << 6) + hd] = f2bf((v[j] + bv) * sc);
        }
      }
    }
  }
}

// ---------- output projection GEMM: fp32 out [M][N] (R17, unchanged) ----------
__global__ __launch_bounds__(512, 4)
void gemm_out(const u16* __restrict__ A, const u16* __restrict__ Bt,
              const float* __restrict__ bias, float* __restrict__ out) {
  __shared__ __align__(16) u16 As[3][128 * 32];
  __shared__ __align__(16) u16 Bs[3][256 * 32];

  const int raw = blockIdx.x;
  const int swz = (raw & 7) * 32 + (raw >> 3);    // bijective: 256 = 8*32
  const int mt = swz >> 2, nt = swz & 3;
  const int m0 = mt * 128, n0 = nt * 256;

  const int tid = threadIdx.x, lane = tid & 63, w = tid >> 6;
  const int wr = w >> 2, wc = w & 3;
  const int c = lane & 15, g = lane >> 4;
  const int arow = tid >> 3;
  const int aus = (tid & 7) ^ (arow & 7);
  const u16* aSrc = A + (size_t)(m0 + arow + 64 * (aus >> 2)) * 1024 + (aus & 3) * 8;
  const u16* bSrc0 = Bt + (size_t)(n0 + arow + 128 * (aus >> 2)) * 1024 + (aus & 3) * 8;
  const u16* bSrc1 = bSrc0 + (size_t)64 * 1024;
  const int ldsOff = w * 1024;
  const int aBr = c * 128 + (((wr * 4 + g) ^ (c & 7)) << 4);
  const int bBr = (wc & 1) * 8192 + c * 128
                  + ((((wc >> 1) * 4 + g) ^ (c & 7)) << 4);

  f32x4 acc[4][4] = {};

#define OSTAGE(BUF, KT_)                                                      \
  {                                                                           \
    gload_lds16(aSrc + (KT_), (char*)As[BUF] + ldsOff);                       \
    gload_lds16(bSrc0 + (KT_), (char*)Bs[BUF] + ldsOff);                      \
    gload_lds16(bSrc1 + (KT_), (char*)Bs[BUF] + 8192 + ldsOff);               \
  }

#define OTILE(BUF, SBUF, KT)                                                  \
  {                                                                           \
    asm volatile("s_waitcnt vmcnt(3)" ::: "memory");                          \
    __builtin_amdgcn_sched_barrier(0);                                        \
    __builtin_amdgcn_s_barrier();                                             \
    __builtin_amdgcn_sched_barrier(0);                                        \
    OSTAGE(SBUF, ((KT) + 64) & 1023);                                         \
    bf16x8 af[4], bfq[4];                                                     \
    _Pragma("unroll")                                                         \
    for (int i = 0; i < 4; ++i)                                               \
      af[i] = *(const bf16x8*)((const char*)As[BUF] + aBr + i * 2048);        \
    _Pragma("unroll")                                                         \
    for (int i = 0; i < 4; ++i)                                               \
      bfq[i] = *(const bf16x8*)((const char*)Bs[BUF] + bBr + i * 2048);       \
    __builtin_amdgcn_s_setprio(1);                                            \
    _Pragma("unroll")                                                         \
    for (int mi = 0; mi < 4; ++mi)                                            \
      _Pragma("unroll")                                                       \
      for (int ni = 0; ni < 4; ++ni)                                          \
        acc[mi][ni] = mfma16(af[mi], bfq[ni], acc[mi][ni]);                   \
    __builtin_amdgcn_s_setprio(0);                                            \
  }

  OSTAGE(0, 0);
  OSTAGE(1, 32);
  for (int kt = 0; kt < 960; kt += 96) {
    OTILE(0, 2, kt);
    OTILE(1, 0, kt + 32);
    OTILE(2, 1, kt + 64);
  }
  OTILE(0, 2, 960);
  OTILE(1, 0, 992);
#undef OTILE
#undef OSTAGE

  #pragma unroll
  for (int mi = 0; mi < 4; ++mi) {
    #pragma unroll
    for (int ni = 0; ni < 4; ++ni) {
      const int n = n0 + wc * 64 + ni * 16 + c;
      const float bv = bias[n];
      const int mb = m0 + wr * 64 + mi * 16 + g * 4;
      const f32x4 v = acc[mi][ni];
      #pragma unroll
      for (int j = 0; j < 4; ++j)
        out[(size_t)(mb + j) * Dn + n] = v[j] + bv;
    }
  }
}

// ---------- flash attention (R16/R17, unchanged) ----------
__global__ __launch_bounds__(512, 4)
void flash_attn(const u16* __restrict__ Q, const u16* __restrict__ K,
                const u16* __restrict__ Vt, u16* __restrict__ X) {
  __shared__ __align__(16) u16 Ks[3][4096];      // 24 KB triple-buffered K
  __shared__ __align__(16) u16 Vs[3][4096];      //  + V tiles

  const int tid = threadIdx.x, lane = tid & 63, w = tid >> 6;   // 8 waves
  const int bid = blockIdx.x;
  const int bh = bid & 63, qt = bid >> 6;
  const int b = bh >> 4, h = bh & 15;
  const int q0 = qt * 128 + w * 16;
  const int c = lane & 15, g = lane >> 4;

  const u16* Qb = Q + (size_t)bh * Sn * 64;
  const u16* Kb = K + (size_t)bh * Sn * 64;
  const u16* Vb = Vt + (size_t)bh * 64 * Sn;

  const int srow = tid >> 3;
  const int scol = (((tid & 7) * 16) ^ ((srow & 7) << 4)) >> 1;   // elements
  const int srcK = srow * 64 + scol;      // + kv*64 per tile
  const int srcV = srow * Sn + scol;      // + kv per tile
  const int ldsOff = w * 1024;            // bytes; HW adds lane*16
#define STAGE(BUF, KV_)                                                   \
  {                                                                       \
    gload_lds16(Kb + (size_t)(KV_) * 64 + srcK, (char*)Ks[BUF] + ldsOff); \
    gload_lds16(Vb + (KV_) + srcV, (char*)Vs[BUF] + ldsOff);              \
  }

  const int laneB0 = c * 128 + ((g * 16) ^ ((c & 7) << 4));
  const int laneB1 = c * 128 + ((64 + g * 16) ^ ((c & 7) << 4));

  bf16x8 qf[2];
  #pragma unroll
  for (int ks = 0; ks < 2; ++ks)
    qf[ks] = *(const bf16x8*)(Qb + (size_t)(q0 + c) * 64 + ks * 32 + g * 8);

  bf16x8 ONES;
  #pragma unroll
  for (int e = 0; e < 8; ++e) ONES[e] = (__bf16)1.0f;
  const f32x4 SINITv = {SSHIFT, SSHIFT, SSHIFT, SSHIFT};

  f32x4 o[4] = {};
  f32x4 lacc = {};              // row-sum l in O layout: q = q0 + g*4 + j
  f32x4 scA[4], scB[4];

#define QK_BLOCK(KB, SCT)                                                     \
  {                                                                           \
    bf16x8 kfr[4];                                                            \
    _Pragma("unroll")                                                         \
    for (int kf = 0; kf < 4; ++kf)                                            \
      kfr[kf] = *(const bf16x8*)((const char*)Ks[KB] + laneB0 + kf * 2048);   \
    __builtin_amdgcn_s_setprio(1);                                            \
    _Pragma("unroll")                                                         \
    for (int kf = 0; kf < 4; ++kf)                                            \
      SCT[kf] = mfma16(kfr[kf], qf[0], SINITv);                               \
    __builtin_amdgcn_s_setprio(0);                                            \
    _Pragma("unroll")                                                         \
    for (int kf = 0; kf < 4; ++kf)                                            \
      kfr[kf] = *(const bf16x8*)((const char*)Ks[KB] + laneB1 + kf * 2048);   \
    __builtin_amdgcn_s_setprio(1);                                            \
    _Pragma("unroll")                                                         \
    for (int kf = 0; kf < 4; ++kf)                                            \
      SCT[kf] = mfma16(kfr[kf], qf[1], SCT[kf]);                              \
    __builtin_amdgcn_s_setprio(0);                                            \
  }

#define FIN_BLOCK(VB, SCT)                                                    \
  {                                                                           \
    uint32_t wvv[4][2];                                                       \
    _Pragma("unroll")                                                         \
    for (int kf = 0; kf < 4; ++kf) {                                          \
      const float p0 = __builtin_exp2f(SCT[kf][0]);                           \
      const float p1 = __builtin_exp2f(SCT[kf][1]);                           \
      const float p2 = __builtin_exp2f(SCT[kf][2]);                           \
      const float p3 = __builtin_exp2f(SCT[kf][3]);                           \
      asm("v_cvt_pk_bf16_f32 %0, %1, %2" : "=v"(wvv[kf][0]) : "v"(p0), "v"(p1)); \
      asm("v_cvt_pk_bf16_f32 %0, %1, %2" : "=v"(wvv[kf][1]) : "v"(p2), "v"(p3)); \
    }                                                                         \
    bf16x8 pa[2];                                                             \
    _Pragma("unroll")                                                         \
    for (int ks2 = 0; ks2 < 2; ++ks2) {                                       \
      uint32_t ua = wvv[2 * ks2][0], ub = wvv[2 * ks2][1];                    \
      uint32_t uc = wvv[2 * ks2 + 1][0], ud = wvv[2 * ks2 + 1][1];            \
      asm("v_permlane32_swap_b32 %0, %1" : "+v"(ua), "+v"(uc));               \
      asm("v_permlane32_swap_b32 %0, %1" : "+v"(ub), "+v"(ud));               \
      asm("v_permlane16_swap_b32 %0, %1" : "+v"(ua), "+v"(uc));               \
      asm("v_permlane16_swap_b32 %0, %1" : "+v"(ub), "+v"(ud));               \
      const u32x4 uv = {ua, ub, uc, ud};                                      \
      pa[ks2] = __builtin_bit_cast(bf16x8, uv);                               \
    }                                                                         \
    lacc = mfma16(pa[0], ONES, lacc);                                         \
    lacc = mfma16(pa[1], ONES, lacc);                                         \
    {                                                                         \
      bf16x8 vfr[4];                                                          \
      _Pragma("unroll")                                                       \
      for (int nd = 0; nd < 4; ++nd)                                          \
        vfr[nd] = *(const bf16x8*)((const char*)Vs[VB] + laneB0 + nd * 2048); \
      __builtin_amdgcn_s_setprio(1);                                          \
      _Pragma("unroll")                                                       \
      for (int nd = 0; nd < 4; ++nd)                                          \
        o[nd] = mfma16(pa[0], vfr[nd], o[nd]);                                \
      __builtin_amdgcn_s_setprio(0);                                          \
      _Pragma("unroll")                                                       \
      for (int nd = 0; nd < 4; ++nd)                                          \
        vfr[nd] = *(const bf16x8*)((const char*)Vs[VB] + laneB1 + nd * 2048); \
      __builtin_amdgcn_s_setprio(1);                                          \
      _Pragma("unroll")                                                       \
      for (int nd = 0; nd < 4; ++nd)                                          \
        o[nd] = mfma16(pa[1], vfr[nd], o[nd]);                                \
      __builtin_amdgcn_s_setprio(0);                                          \
    }                                                                         \
  }

#define PIPE(KB, VB, SB, KV, CURT, NXTT)                                      \
  {                                                                           \
    asm volatile("s_waitcnt vmcnt(0)" ::: "memory");                          \
    __builtin_amdgcn_sched_barrier(0);                                        \
    __builtin_amdgcn_s_barrier();                                             \
    __builtin_amdgcn_sched_barrier(0);                                        \
    STAGE(SB, (KV) + 128);                                                    \
    QK_BLOCK(KB, NXTT);                                                       \
    FIN_BLOCK(VB, CURT);                                                      \
  }

  // prologue: stage tiles 0,1; QK(0) -> scA
  STAGE(0, 0);
  STAGE(1, 64);
  asm volatile("s_waitcnt vmcnt(2)" ::: "memory");   // stage(0) landed
  __builtin_amdgcn_sched_barrier(0);
  __builtin_amdgcn_s_barrier();
  __builtin_amdgcn_sched_barrier(0);
  QK_BLOCK(0, scA);

  // t = 0..29 (staged), 5 x 6-period unroll
  for (int kv = 0; kv < 1920; kv += 384) {
    PIPE(1, 0, 2, kv,       scA, scB);
    PIPE(2, 1, 0, kv + 64,  scB, scA);
    PIPE(0, 2, 1, kv + 128, scA, scB);
    PIPE(1, 0, 2, kv + 192, scB, scA);
    PIPE(2, 1, 0, kv + 256, scA, scB);
    PIPE(0, 2, 1, kv + 320, scB, scA);
  }
  // t = 30: no stage (tile 31 already staged to buf 1 at t=29)
  asm volatile("s_waitcnt vmcnt(0)" ::: "memory");
  __builtin_amdgcn_sched_barrier(0);
  __builtin_amdgcn_s_barrier();
  __builtin_amdgcn_sched_barrier(0);
  QK_BLOCK(1, scB);       // tile 31 from Ks[1]
  FIN_BLOCK(0, scA);      // tile 30 from Vs[0]
  // tail t = 31: finish only; tile 31 lives in buffer 31%3 = 1
  FIN_BLOCK(1, scB);
#undef PIPE
#undef FIN_BLOCK
#undef QK_BLOCK
#undef STAGE

  // epilogue: l already in O layout; normalize and store
  #pragma unroll
  for (int j = 0; j < 4; ++j) {
    const float rn = 1.0f / lacc[j];
    const int s = q0 + g * 4 + j;
    u16* dst = X + (size_t)(b * Sn + s) * Dn + h * 64 + c;
    #pragma unroll
    for (int nd = 0; nd < 4; ++nd)
      dst[nd * 16] = f2bf(o[nd][j] * rn);
  }
}

// ---------- launch ----------
extern "C" void kernel_launch(void* const* d_in, const int* in_sizes, int n_in,
                              void* d_out, int out_size, void* d_ws, size_t ws_size,
                              hipStream_t stream) {
  (void)in_sizes; (void)n_in; (void)out_size; (void)ws_size;
  const float* query = (const float*)d_in[0];
  const float* key_  = (const float*)d_in[1];
  const float* value = (const float*)d_in[2];
  const float* Wq = (const float*)d_in[3];
  const float* bq = (const float*)d_in[4];
  const float* Wk = (const float*)d_in[5];
  const float* bk = (const float*)d_in[6];
  const float* Wv = (const float*)d_in[7];
  const float* bv = (const float*)d_in[8];
  const float* Wo = (const float*)d_in[9];
  const float* bo = (const float*)d_in[10];

  char* ws = (char*)d_ws;
  size_t off = 0;
  auto alloc = [&](size_t bytes) {
    void* p = ws + off;
    off += (bytes + 255) & ~(size_t)255;
    return p;
  };
  const size_t actB = (size_t)Mn * Dn * 2;   // 16 MB
  const size_t wB = (size_t)Dn * Dn * 2;     // 2 MB
  u16* wqb = (u16*)alloc(wB);
  u16* wkb = (u16*)alloc(wB);
  u16* wvb = (u16*)alloc(wB);
  u16* wob = (u16*)alloc(wB);
  u16* Qh = (u16*)alloc(actB);
  u16* Kh = (u16*)alloc(actB);
  u16* Vt = (u16*)alloc(actB);
  u16* Xb = (u16*)alloc(actB);

  CastArgs ca;
  ca.src[0] = Wq; ca.src[1] = Wk; ca.src[2] = Wv; ca.src[3] = Wo;
  ca.dst[0] = wqb; ca.dst[1] = wkb; ca.dst[2] = wvb; ca.dst[3] = wob;
  ca.n[0] = ca.n[1] = ca.n[2] = ca.n[3] = Dn * Dn;
  cast_kernel<<<dim3(512, 4), 256, 0, stream>>>(ca);

  QKVArgs qa;
  qa.Aq = query; qa.Ak = key_; qa.Av = value;
  qa.Wq = wqb; qa.Wk = wkb; qa.Wv = wvb;
  qa.bq = bq; qa.bk = bk; qa.bv = bv;
  qa.Qh = Qh; qa.Kh = Kh; qa.Vt = Vt;
  qkv_gemm<<<dim3(1536), 512, 0, stream>>>(qa);

  flash_attn<<<dim3(Bn * Hn * (Sn / 128)), 512, 0, stream>>>(Qh, Kh, Vt, Xb);
  gemm_out<<<dim3(256), 512, 0, stream>>>(Xb, wob, bo, (float*)d_out);
}